// Round 1
// baseline (227.286 us; speedup 1.0000x reference)
//
#include <hip/hip_runtime.h>
#include <math.h>

#define B_N 8192
#define E_N 512
#define T_N 32

// ws layout (in ints):
// [0,32)   counts
// [32,64)  cursor
// [64,97)  offs (T+1)
// [128,8320)  order (B)
// [8320,16512) yacc (B floats)

__global__ void k_init(int* wsi, float* yacc) {
    int i = blockIdx.x * blockDim.x + threadIdx.x;
    if (i < 64) wsi[i] = 0;
    if (i < B_N) yacc[i] = 0.f;
}

__global__ void k_hist(const int* __restrict__ tv, int* __restrict__ counts) {
    int b = blockIdx.x * blockDim.x + threadIdx.x;
    if (b < B_N) atomicAdd(&counts[tv[b]], 1);
}

__global__ void k_offs(const int* __restrict__ counts, int* __restrict__ offs) {
    if (threadIdx.x == 0) {
        int acc = 0;
        for (int t = 0; t < T_N; ++t) { offs[t] = acc; acc += counts[t]; }
        offs[T_N] = acc;
    }
}

__global__ void k_scatter(const int* __restrict__ tv, const int* __restrict__ offs,
                          int* __restrict__ cursor, int* __restrict__ order) {
    int b = blockIdx.x * blockDim.x + threadIdx.x;
    if (b < B_N) {
        int t = tv[b];
        int pos = offs[t] + atomicAdd(&cursor[t], 1);
        order[pos] = b;
    }
}

// GEMM tile: TM=64 rows (samples), TN=128 cols (h), TK=32.
// 256 threads = 16 (ty: row groups of 4) x 16 (tx: col groups of 8, split 4+4).
__global__ __launch_bounds__(256) void k_gemm(
    const float* __restrict__ g_exp, const float* __restrict__ W1,
    const float* __restrict__ b1, const float* __restrict__ W2,
    const int* __restrict__ offs, const int* __restrict__ order,
    float* __restrict__ yacc) {
    int t = blockIdx.z;
    int base = offs[t];
    int n_t = offs[t + 1] - base;
    int m0 = blockIdx.y * 64;
    if (m0 >= n_t) return;
    int n0 = blockIdx.x * 128;

    __shared__ float As[32][68];   // transposed: As[k][row], pad 68 (272B rows, 16B aligned)
    __shared__ float Bs[32][128];  // Bs[k][col]
    __shared__ int sidx[64];

    int tid = threadIdx.x;
    if (tid < 64) {
        int m = m0 + tid;
        sidx[tid] = (m < n_t) ? order[base + m] : -1;
    }
    __syncthreads();

    int ty = tid >> 4;   // 0..15, rows ty*4..ty*4+3
    int tx = tid & 15;   // 0..15, cols tx*4..tx*4+3 and tx*4+64..tx*4+67

    float acc[4][8];
#pragma unroll
    for (int r = 0; r < 4; ++r)
#pragma unroll
        for (int c = 0; c < 8; ++c) acc[r][c] = 0.f;

    for (int k0 = 0; k0 < E_N; k0 += 32) {
        // Load A tile: 64 rows x 32 k = 512 float4 slots (8 lanes per row chunk)
#pragma unroll
        for (int p = 0; p < 2; ++p) {
            int idx = tid + 256 * p;
            int row = idx >> 3;       // 0..63
            int kc  = idx & 7;        // float4 index within TK
            int s = sidx[row];
            float4 v = make_float4(0.f, 0.f, 0.f, 0.f);
            if (s >= 0)
                v = *(const float4*)(g_exp + (size_t)s * E_N + k0 + kc * 4);
            As[kc * 4 + 0][row] = v.x;
            As[kc * 4 + 1][row] = v.y;
            As[kc * 4 + 2][row] = v.z;
            As[kc * 4 + 3][row] = v.w;
        }
        // Load B tile: 32 k x 128 cols = 1024 float4 slots
#pragma unroll
        for (int p = 0; p < 4; ++p) {
            int idx = tid + 256 * p;
            int kr = idx >> 5;        // 0..31
            int c4 = idx & 31;        // 0..31 (float4 col group)
            *(float4*)(&Bs[kr][c4 * 4]) =
                *(const float4*)(W1 + ((size_t)t * E_N + (k0 + kr)) * E_N + n0 + c4 * 4);
        }
        __syncthreads();

#pragma unroll
        for (int e = 0; e < 32; ++e) {
            float4 a  = *(const float4*)(&As[e][ty * 4]);
            float4 bA = *(const float4*)(&Bs[e][tx * 4]);
            float4 bB = *(const float4*)(&Bs[e][tx * 4 + 64]);
            float av[4] = {a.x, a.y, a.z, a.w};
            float bv[8] = {bA.x, bA.y, bA.z, bA.w, bB.x, bB.y, bB.z, bB.w};
#pragma unroll
            for (int r = 0; r < 4; ++r)
#pragma unroll
                for (int c = 0; c < 8; ++c)
                    acc[r][c] = fmaf(av[r], bv[c], acc[r][c]);
        }
        __syncthreads();
    }

    // Epilogue: u + b1 -> gelu(exact) -> * W2, partial dot over this block's 128 cols
    float pr[4] = {0.f, 0.f, 0.f, 0.f};
#pragma unroll
    for (int c = 0; c < 8; ++c) {
        int n = n0 + tx * 4 + ((c >= 4) ? 64 : 0) + (c & 3);
        float bb = b1[t * E_N + n];
        float w2 = W2[t * E_N + n];
#pragma unroll
        for (int r = 0; r < 4; ++r) {
            float u = acc[r][c] + bb;
            float g = 0.5f * u * (1.f + erff(u * 0.70710678118654752f));
            pr[r] = fmaf(g, w2, pr[r]);
        }
    }
    // Reduce across the 16 tx lanes sharing a row group (lanes are 16-aligned groups)
#pragma unroll
    for (int off = 8; off >= 1; off >>= 1)
#pragma unroll
        for (int r = 0; r < 4; ++r) pr[r] += __shfl_xor(pr[r], off, 64);

    if (tx == 0) {
#pragma unroll
        for (int r = 0; r < 4; ++r) {
            int m = m0 + ty * 4 + r;
            if (m < n_t) atomicAdd(&yacc[sidx[ty * 4 + r]], pr[r]);
        }
    }
}

__global__ void k_final(const float* __restrict__ yacc, const int* __restrict__ tv,
                        const float* __restrict__ b2, float* __restrict__ out) {
    int b = blockIdx.x * blockDim.x + threadIdx.x;
    if (b < B_N) {
        float x = yacc[b] + b2[tv[b]];
        // stable softplus
        out[b] = fmaxf(x, 0.f) + log1pf(expf(-fabsf(x)));
    }
}

extern "C" void kernel_launch(void* const* d_in, const int* in_sizes, int n_in,
                              void* d_out, int out_size, void* d_ws, size_t ws_size,
                              hipStream_t stream) {
    const float* g_exp = (const float*)d_in[0];
    const int*   tv    = (const int*)d_in[1];
    const float* W1    = (const float*)d_in[2];
    const float* b1    = (const float*)d_in[3];
    const float* W2    = (const float*)d_in[4];
    const float* b2    = (const float*)d_in[5];
    float* out = (float*)d_out;

    int* wsi    = (int*)d_ws;
    int* counts = wsi;
    int* cursor = wsi + 32;
    int* offs   = wsi + 64;
    int* order  = wsi + 128;
    float* yacc = (float*)(wsi + 8320);

    k_init<<<32, 256, 0, stream>>>(wsi, yacc);
    k_hist<<<32, 256, 0, stream>>>(tv, counts);
    k_offs<<<1, 64, 0, stream>>>(counts, offs);
    k_scatter<<<32, 256, 0, stream>>>(tv, offs, cursor, order);
    k_gemm<<<dim3(4, 8, 32), 256, 0, stream>>>(g_exp, W1, b1, W2, offs, order, yacc);
    k_final<<<32, 256, 0, stream>>>(yacc, tv, b2, out);
}

// Round 2
// 157.510 us; speedup vs baseline: 1.4430x; 1.4430x over previous
//
#include <hip/hip_runtime.h>
#include <math.h>

#define B_N 8192
#define E_N 512
#define T_N 32
#define LDA 40  // LDS row pitch in bf16 elems (32 + 8 pad)

typedef short bf16x8 __attribute__((ext_vector_type(8)));
typedef float f32x4 __attribute__((ext_vector_type(4)));

// ---------------- ws layout (bytes) ----------------
// 0      : counts[32] + cursor[32]          (256 B)
// 256    : offs[33]                         (pad to 256)
// 512    : rank[8192]  (b -> sorted pos)    (32 KB)
// 33280  : order[8192] (sorted pos -> b)    (32 KB)
// 66048  : yacc[8192] floats (sorted order) (32 KB)
// 98816  : Asort bf16 [8192][512]           (8 MB)
// 8487424: W1T bf16 [32][512][512] (n-major)(16 MB)
#define WS_OFFS   256
#define WS_RANK   512
#define WS_ORDER  33280
#define WS_YACC   66048
#define WS_ASORT  98816
#define WS_W1T    8487424
#define WS_REQ    25264640

static __device__ __forceinline__ unsigned short f2bf(float f) {
    unsigned int u = __float_as_uint(f);
    unsigned int r = u + 0x7fffu + ((u >> 16) & 1u);  // RNE
    return (unsigned short)(r >> 16);
}

__global__ void k_init(int* wsi, float* yacc) {
    int i = blockIdx.x * blockDim.x + threadIdx.x;
    if (i < 64) wsi[i] = 0;
    if (i < B_N) yacc[i] = 0.f;
}

__global__ void k_hist(const int* __restrict__ tv, int* __restrict__ counts) {
    __shared__ int lh[T_N];
    int tid = threadIdx.x;
    if (tid < T_N) lh[tid] = 0;
    __syncthreads();
    int b = blockIdx.x * 256 + tid;
    atomicAdd(&lh[tv[b]], 1);
    __syncthreads();
    if (tid < T_N && lh[tid] > 0) atomicAdd(&counts[tid], lh[tid]);
}

__global__ void k_offs(const int* __restrict__ counts, int* __restrict__ offs) {
    int lane = threadIdx.x;  // 64 threads
    int c = (lane < T_N) ? counts[lane] : 0;
    int excl = 0;
#pragma unroll
    for (int i = 0; i < T_N; ++i) {
        int v = __shfl(c, i, 64);
        if (i < lane) excl += v;
    }
    if (lane < T_N) offs[lane] = excl;
    if (lane == T_N) offs[T_N] = excl;  // lane 32: excl = total
}

// scatter (block-aggregated atomics) + gather g_exp rows into sorted order as bf16
__global__ __launch_bounds__(256) void k_scatter_gather(
    const float* __restrict__ g_exp, const int* __restrict__ tv,
    const int* __restrict__ offs, int* __restrict__ cursor,
    int* __restrict__ rank, int* __restrict__ order,
    unsigned short* __restrict__ Asort) {
    __shared__ int lh[T_N], lbase[T_N];
    __shared__ int spos[256];
    int tid = threadIdx.x;
    int b = blockIdx.x * 256 + tid;
    if (tid < T_N) lh[tid] = 0;
    __syncthreads();
    int t = tv[b];
    int lpos = atomicAdd(&lh[t], 1);
    __syncthreads();
    if (tid < T_N && lh[tid] > 0) lbase[tid] = atomicAdd(&cursor[tid], lh[tid]);
    __syncthreads();
    int pos = offs[t] + lbase[t] + lpos;
    rank[b] = pos;
    order[pos] = b;
    spos[tid] = pos;
    __syncthreads();
    const float* src = g_exp + (size_t)blockIdx.x * 256 * E_N;
#pragma unroll 4
    for (int p = 0; p < 128; ++p) {
        int idx = p * 256 + tid;          // 256 rows x 128 float4-chunks
        int row = idx >> 7, c = idx & 127;
        float4 v = *(const float4*)(src + (size_t)row * E_N + c * 4);
        ushort4 o;
        o.x = f2bf(v.x); o.y = f2bf(v.y); o.z = f2bf(v.z); o.w = f2bf(v.w);
        *(ushort4*)(Asort + (size_t)spos[row] * E_N + c * 4) = o;
    }
}

// W1[t][k][n] fp32 -> W1T[t][n][k] bf16, 64x64 LDS transpose tiles
__global__ __launch_bounds__(256) void k_w1t(const float* __restrict__ W1,
                                             unsigned short* __restrict__ W1T) {
    __shared__ float T[64][65];
    int t = blockIdx.z, k0 = blockIdx.y * 64, n0 = blockIdx.x * 64;
    int tid = threadIdx.x;
    int g = tid >> 4, c = tid & 15;
#pragma unroll
    for (int p = 0; p < 4; ++p) {
        int row = p * 16 + g;  // k within tile
        float4 v = *(const float4*)(W1 + ((size_t)t * E_N + k0 + row) * E_N + n0 + c * 4);
        T[c * 4 + 0][row] = v.x;
        T[c * 4 + 1][row] = v.y;
        T[c * 4 + 2][row] = v.z;
        T[c * 4 + 3][row] = v.w;
    }
    __syncthreads();
#pragma unroll
    for (int p = 0; p < 4; ++p) {
        int n = p * 16 + g;
        ushort4 o;
        o.x = f2bf(T[n][c * 4 + 0]);
        o.y = f2bf(T[n][c * 4 + 1]);
        o.z = f2bf(T[n][c * 4 + 2]);
        o.w = f2bf(T[n][c * 4 + 3]);
        *(ushort4*)(W1T + ((size_t)t * E_N + n0 + n) * E_N + k0 + c * 4) = o;
    }
}

// MFMA GEMM: per (tissue, 128-row tile, 128-col tile); fused gelu*W2 epilogue.
__global__ __launch_bounds__(256) void k_gemm_mfma(
    const unsigned short* __restrict__ Asort, const unsigned short* __restrict__ W1T,
    const float* __restrict__ b1, const float* __restrict__ W2,
    const int* __restrict__ offs, float* __restrict__ yacc) {
    int t = blockIdx.z;
    int base = offs[t];
    int n_t = offs[t + 1] - base;
    int m0 = blockIdx.y * 128;
    if (m0 >= n_t) return;
    int n0 = blockIdx.x * 128;

    __shared__ __align__(16) unsigned short As[128 * LDA];
    __shared__ __align__(16) unsigned short Bs[128 * LDA];

    int tid = threadIdx.x;
    int wave = tid >> 6, lane = tid & 63;
    int quad = lane >> 4, l15 = lane & 15;
    int wm = (wave >> 1) * 64, wn = (wave & 1) * 64;

    f32x4 acc[4][4];
#pragma unroll
    for (int mi = 0; mi < 4; ++mi)
#pragma unroll
        for (int ni = 0; ni < 4; ++ni) acc[mi][ni] = (f32x4){0.f, 0.f, 0.f, 0.f};

    const unsigned short* Bsrc = W1T + ((size_t)t * E_N + n0) * E_N;

    for (int k0 = 0; k0 < E_N; k0 += 32) {
#pragma unroll
        for (int p = 0; p < 2; ++p) {
            int idx = tid + 256 * p;
            int row = idx >> 2, c = idx & 3;  // c: 16B chunk (8 bf16)
            int arow = base + m0 + row;
            if (arow > B_N - 1) arow = B_N - 1;  // tail rows read garbage, predicated out later
            int4 av = *(const int4*)(Asort + (size_t)arow * E_N + k0 + c * 8);
            *(int4*)(As + row * LDA + c * 8) = av;
            int4 bv = *(const int4*)(Bsrc + (size_t)row * E_N + k0 + c * 8);
            *(int4*)(Bs + row * LDA + c * 8) = bv;
        }
        __syncthreads();
        bf16x8 af[4], bf[4];
#pragma unroll
        for (int i = 0; i < 4; ++i) {
            af[i] = *(const bf16x8*)(As + (wm + i * 16 + l15) * LDA + quad * 8);
            bf[i] = *(const bf16x8*)(Bs + (wn + i * 16 + l15) * LDA + quad * 8);
        }
#pragma unroll
        for (int mi = 0; mi < 4; ++mi)
#pragma unroll
            for (int ni = 0; ni < 4; ++ni)
                acc[mi][ni] = __builtin_amdgcn_mfma_f32_16x16x32_bf16(
                    af[mi], bf[ni], acc[mi][ni], 0, 0, 0);
        __syncthreads();
    }

    // epilogue: gelu(acc + b1) * W2, partial dot over this block's 128 cols
    float pr[4][4];  // [mi][r]
#pragma unroll
    for (int mi = 0; mi < 4; ++mi)
#pragma unroll
        for (int r = 0; r < 4; ++r) pr[mi][r] = 0.f;
#pragma unroll
    for (int ni = 0; ni < 4; ++ni) {
        int n = n0 + wn + ni * 16 + l15;
        float bb = b1[t * E_N + n];
        float w2 = W2[t * E_N + n];
#pragma unroll
        for (int mi = 0; mi < 4; ++mi)
#pragma unroll
            for (int r = 0; r < 4; ++r) {
                float u = acc[mi][ni][r] + bb;
                float gg = 0.5f * u * (1.f + erff(u * 0.70710678118654752f));
                pr[mi][r] = fmaf(gg, w2, pr[mi][r]);
            }
    }
#pragma unroll
    for (int off = 1; off <= 8; off <<= 1)
#pragma unroll
        for (int mi = 0; mi < 4; ++mi)
#pragma unroll
            for (int r = 0; r < 4; ++r) pr[mi][r] += __shfl_xor(pr[mi][r], off, 64);

    if (l15 == 0) {
#pragma unroll
        for (int mi = 0; mi < 4; ++mi)
#pragma unroll
            for (int r = 0; r < 4; ++r) {
                int row = m0 + wm + mi * 16 + quad * 4 + r;
                if (row < n_t) atomicAdd(&yacc[base + row], pr[mi][r]);
            }
    }
}

__global__ void k_final(const float* __restrict__ yacc, const int* __restrict__ rank,
                        const int* __restrict__ tv, const float* __restrict__ b2,
                        float* __restrict__ out, int use_rank) {
    int b = blockIdx.x * blockDim.x + threadIdx.x;
    if (b < B_N) {
        int idx = use_rank ? rank[b] : b;
        float x = yacc[idx] + b2[tv[b]];
        out[b] = fmaxf(x, 0.f) + log1pf(expf(-fabsf(x)));  // stable softplus
    }
}

// ================= fallback (round-1 fp32 path, proven) =================
__global__ void fb_scatter(const int* __restrict__ tv, const int* __restrict__ offs,
                           int* __restrict__ cursor, int* __restrict__ order) {
    int b = blockIdx.x * blockDim.x + threadIdx.x;
    if (b < B_N) {
        int t = tv[b];
        int pos = offs[t] + atomicAdd(&cursor[t], 1);
        order[pos] = b;
    }
}

__global__ __launch_bounds__(256) void fb_gemm(
    const float* __restrict__ g_exp, const float* __restrict__ W1,
    const float* __restrict__ b1, const float* __restrict__ W2,
    const int* __restrict__ offs, const int* __restrict__ order,
    float* __restrict__ yacc) {
    int t = blockIdx.z;
    int base = offs[t];
    int n_t = offs[t + 1] - base;
    int m0 = blockIdx.y * 64;
    if (m0 >= n_t) return;
    int n0 = blockIdx.x * 128;

    __shared__ float As[32][68];
    __shared__ float Bs[32][128];
    __shared__ int sidx[64];

    int tid = threadIdx.x;
    if (tid < 64) {
        int m = m0 + tid;
        sidx[tid] = (m < n_t) ? order[base + m] : -1;
    }
    __syncthreads();

    int ty = tid >> 4, tx = tid & 15;
    float acc[4][8];
#pragma unroll
    for (int r = 0; r < 4; ++r)
#pragma unroll
        for (int c = 0; c < 8; ++c) acc[r][c] = 0.f;

    for (int k0 = 0; k0 < E_N; k0 += 32) {
#pragma unroll
        for (int p = 0; p < 2; ++p) {
            int idx = tid + 256 * p;
            int row = idx >> 3, kc = idx & 7;
            int s = sidx[row];
            float4 v = make_float4(0.f, 0.f, 0.f, 0.f);
            if (s >= 0) v = *(const float4*)(g_exp + (size_t)s * E_N + k0 + kc * 4);
            As[kc * 4 + 0][row] = v.x;
            As[kc * 4 + 1][row] = v.y;
            As[kc * 4 + 2][row] = v.z;
            As[kc * 4 + 3][row] = v.w;
        }
#pragma unroll
        for (int p = 0; p < 4; ++p) {
            int idx = tid + 256 * p;
            int kr = idx >> 5, c4 = idx & 31;
            *(float4*)(&Bs[kr][c4 * 4]) =
                *(const float4*)(W1 + ((size_t)t * E_N + (k0 + kr)) * E_N + n0 + c4 * 4);
        }
        __syncthreads();
#pragma unroll
        for (int e = 0; e < 32; ++e) {
            float4 a = *(const float4*)(&As[e][ty * 4]);
            float4 bA = *(const float4*)(&Bs[e][tx * 4]);
            float4 bB = *(const float4*)(&Bs[e][tx * 4 + 64]);
            float av[4] = {a.x, a.y, a.z, a.w};
            float bv[8] = {bA.x, bA.y, bA.z, bA.w, bB.x, bB.y, bB.z, bB.w};
#pragma unroll
            for (int r = 0; r < 4; ++r)
#pragma unroll
                for (int c = 0; c < 8; ++c) acc[r][c] = fmaf(av[r], bv[c], acc[r][c]);
        }
        __syncthreads();
    }

    float pr[4] = {0.f, 0.f, 0.f, 0.f};
#pragma unroll
    for (int c = 0; c < 8; ++c) {
        int n = n0 + tx * 4 + ((c >= 4) ? 64 : 0) + (c & 3);
        float bb = b1[t * E_N + n];
        float w2 = W2[t * E_N + n];
#pragma unroll
        for (int r = 0; r < 4; ++r) {
            float u = acc[r][c] + bb;
            float g = 0.5f * u * (1.f + erff(u * 0.70710678118654752f));
            pr[r] = fmaf(g, w2, pr[r]);
        }
    }
#pragma unroll
    for (int off = 8; off >= 1; off >>= 1)
#pragma unroll
        for (int r = 0; r < 4; ++r) pr[r] += __shfl_xor(pr[r], off, 64);

    if (tx == 0) {
#pragma unroll
        for (int r = 0; r < 4; ++r) {
            int m = m0 + ty * 4 + r;
            if (m < n_t) atomicAdd(&yacc[sidx[ty * 4 + r]], pr[r]);
        }
    }
}

extern "C" void kernel_launch(void* const* d_in, const int* in_sizes, int n_in,
                              void* d_out, int out_size, void* d_ws, size_t ws_size,
                              hipStream_t stream) {
    const float* g_exp = (const float*)d_in[0];
    const int*   tv    = (const int*)d_in[1];
    const float* W1    = (const float*)d_in[2];
    const float* b1    = (const float*)d_in[3];
    const float* W2    = (const float*)d_in[4];
    const float* b2    = (const float*)d_in[5];
    float* out = (float*)d_out;

    char* ws = (char*)d_ws;
    int* counts = (int*)ws;
    int* cursor = counts + 32;
    int* offs   = (int*)(ws + WS_OFFS);
    int* rank   = (int*)(ws + WS_RANK);
    int* order  = (int*)(ws + WS_ORDER);
    float* yacc = (float*)(ws + WS_YACC);

    if (ws_size >= (size_t)WS_REQ) {
        unsigned short* Asort = (unsigned short*)(ws + WS_ASORT);
        unsigned short* W1T   = (unsigned short*)(ws + WS_W1T);
        k_init<<<32, 256, 0, stream>>>(counts, yacc);
        k_hist<<<32, 256, 0, stream>>>(tv, counts);
        k_offs<<<1, 64, 0, stream>>>(counts, offs);
        k_scatter_gather<<<32, 256, 0, stream>>>(g_exp, tv, offs, cursor, rank, order, Asort);
        k_w1t<<<dim3(8, 8, 32), 256, 0, stream>>>(W1, W1T);
        k_gemm_mfma<<<dim3(4, 4, 32), 256, 0, stream>>>(Asort, W1T, b1, W2, offs, yacc);
        k_final<<<32, 256, 0, stream>>>(yacc, rank, tv, b2, out, 1);
    } else {
        k_init<<<32, 256, 0, stream>>>(counts, yacc);
        k_hist<<<32, 256, 0, stream>>>(tv, counts);
        k_offs<<<1, 64, 0, stream>>>(counts, offs);
        fb_scatter<<<32, 256, 0, stream>>>(tv, offs, cursor, order);
        fb_gemm<<<dim3(4, 8, 32), 256, 0, stream>>>(g_exp, W1, b1, W2, offs, order, yacc);
        k_final<<<32, 256, 0, stream>>>(yacc, rank, tv, b2, out, 0);
    }
}

// Round 3
// 137.230 us; speedup vs baseline: 1.6562x; 1.1478x over previous
//
#include <hip/hip_runtime.h>
#include <math.h>

#define B_N 8192
#define E_N 512
#define T_N 32
#define LDA 40  // LDS row pitch in bf16 elems (32 + 8 pad)

typedef short bf16x8 __attribute__((ext_vector_type(8)));
typedef float f32x4 __attribute__((ext_vector_type(4)));

// ---------------- ws layout (bytes) ----------------
#define WS_OFFS   256
#define WS_RANK   512
#define WS_ORDER  33280
#define WS_YACC   66048
#define WS_ASORT  98816
#define WS_W1T    8487424
#define WS_REQ    25264640

static __device__ __forceinline__ unsigned short f2bf(float f) {
    unsigned int u = __float_as_uint(f);
    unsigned int r = u + 0x7fffu + ((u >> 16) & 1u);  // RNE
    return (unsigned short)(r >> 16);
}

// hist + scan + rank/order + yacc zero, one block of 1024 threads.
__global__ __launch_bounds__(1024) void k_prep(
    const int* __restrict__ tv, int* __restrict__ offs_g,
    int* __restrict__ rank, int* __restrict__ order, float* __restrict__ yacc) {
    __shared__ int lh[16 * 32];    // per-wave histograms
    __shared__ int wcur[16 * 32];  // per-wave cursors
    __shared__ int offs_s[33];
    int tid = threadIdx.x;
    int w = tid >> 6;
    if (tid < 512) { lh[tid] = 0; }
    __syncthreads();
    int tval[8];
#pragma unroll
    for (int c = 0; c < 8; ++c) tval[c] = tv[c * 1024 + tid];
#pragma unroll
    for (int c = 0; c < 8; ++c) atomicAdd(&lh[w * 32 + tval[c]], 1);
    __syncthreads();
    if (tid < 32) {
        int s = 0;
#pragma unroll
        for (int ww = 0; ww < 16; ++ww) s += lh[ww * 32 + tid];
        int excl = 0;
#pragma unroll
        for (int i = 0; i < 32; ++i) {
            int v = __shfl(s, i, 64);
            if (i < tid) excl += v;
        }
        offs_s[tid] = excl;
        offs_g[tid] = excl;
        if (tid == 31) { offs_s[32] = excl + s; offs_g[32] = excl + s; }
    }
    __syncthreads();
    if (tid < 512) {
        int ww = tid >> 5, t = tid & 31;
        int s = offs_s[t];
        for (int w2 = 0; w2 < ww; ++w2) s += lh[w2 * 32 + t];
        wcur[ww * 32 + t] = s;
    }
    __syncthreads();
#pragma unroll
    for (int c = 0; c < 8; ++c) {
        int b = c * 1024 + tid;
        int pos = atomicAdd(&wcur[w * 32 + tval[c]], 1);
        rank[b] = pos;
        order[pos] = b;
    }
#pragma unroll
    for (int c = 0; c < 8; ++c) yacc[c * 1024 + tid] = 0.f;
}

// Fused: blocks [0,2048): W1[t][k][n] fp32 -> W1T[t][n][k] bf16 (64x64 LDS transpose)
//        blocks [2048,2304): gather g_exp rows into sorted order as bf16 (32 rows/block)
__global__ __launch_bounds__(256) void k_convert(
    const float* __restrict__ W1, unsigned short* __restrict__ W1T,
    const float* __restrict__ g_exp, const int* __restrict__ rank,
    unsigned short* __restrict__ Asort) {
    int cid = blockIdx.x;
    int tid = threadIdx.x;
    if (cid < 2048) {
        __shared__ float T[64][65];
        int t = cid >> 6, r = cid & 63;
        int k0 = (r >> 3) * 64, n0 = (r & 7) * 64;
        int g = tid >> 4, c = tid & 15;
#pragma unroll
        for (int p = 0; p < 4; ++p) {
            int row = p * 16 + g;  // k within tile
            float4 v = *(const float4*)(W1 + ((size_t)t * E_N + k0 + row) * E_N + n0 + c * 4);
            T[c * 4 + 0][row] = v.x;
            T[c * 4 + 1][row] = v.y;
            T[c * 4 + 2][row] = v.z;
            T[c * 4 + 3][row] = v.w;
        }
        __syncthreads();
#pragma unroll
        for (int p = 0; p < 4; ++p) {
            int n = p * 16 + g;
            ushort4 o;
            o.x = f2bf(T[n][c * 4 + 0]);
            o.y = f2bf(T[n][c * 4 + 1]);
            o.z = f2bf(T[n][c * 4 + 2]);
            o.w = f2bf(T[n][c * 4 + 3]);
            *(ushort4*)(W1T + ((size_t)t * E_N + n0 + n) * E_N + k0 + c * 4) = o;
        }
    } else {
        int b0 = (cid - 2048) * 32;
#pragma unroll 4
        for (int pp = 0; pp < 16; ++pp) {
            int idx = pp * 256 + tid;
            int row = idx >> 7, c = idx & 127;  // 32 rows x 128 float4-chunks
            int b = b0 + row;
            float4 v = *(const float4*)(g_exp + (size_t)b * E_N + c * 4);
            ushort4 o;
            o.x = f2bf(v.x); o.y = f2bf(v.y); o.z = f2bf(v.z); o.w = f2bf(v.w);
            *(ushort4*)(Asort + (size_t)rank[b] * E_N + c * 4) = o;
        }
    }
}

// MFMA GEMM v2: flat work list, double-buffered LDS, 1 barrier/iter, fused epilogue.
__global__ __launch_bounds__(256) void k_gemm_mfma(
    const unsigned short* __restrict__ Asort, const unsigned short* __restrict__ W1T,
    const float* __restrict__ b1, const float* __restrict__ W2,
    const int* __restrict__ offs, float* __restrict__ yacc) {
    int wi = blockIdx.x;
    int mt = wi >> 7;          // slowest: m-tile (0..3) — actives pack onto distinct CUs
    int rem = wi & 127;
    int t = rem >> 2, nt = rem & 3;
    int base = offs[t];
    int n_t = offs[t + 1] - base;
    int m0 = mt * 128;
    if (m0 >= n_t) return;
    int n0 = nt * 128;

    __shared__ __align__(16) unsigned short As[2][128 * LDA];
    __shared__ __align__(16) unsigned short Bs[2][128 * LDA];

    int tid = threadIdx.x;
    int wave = tid >> 6, lane = tid & 63;
    int quad = lane >> 4, l15 = lane & 15;
    int wm = (wave >> 1) * 64, wn = (wave & 1) * 64;

    // staging indices (2 x 16B chunks per thread per matrix)
    int s_row0 = tid >> 2, s_c = tid & 3;           // p=0: rows 0..63
    int s_row1 = s_row0 + 64;                       // p=1: rows 64..127
    int gr0 = base + m0 + s_row0; if (gr0 > B_N - 1) gr0 = B_N - 1;
    int gr1 = base + m0 + s_row1; if (gr1 > B_N - 1) gr1 = B_N - 1;
    const unsigned short* Bsrc = W1T + ((size_t)t * E_N + n0) * E_N;
    const unsigned short* a0p = Asort + (size_t)gr0 * E_N + s_c * 8;
    const unsigned short* a1p = Asort + (size_t)gr1 * E_N + s_c * 8;
    const unsigned short* b0p = Bsrc + (size_t)s_row0 * E_N + s_c * 8;
    const unsigned short* b1p = Bsrc + (size_t)s_row1 * E_N + s_c * 8;

    f32x4 acc[4][4];
#pragma unroll
    for (int mi = 0; mi < 4; ++mi)
#pragma unroll
        for (int ni = 0; ni < 4; ++ni) acc[mi][ni] = (f32x4){0.f, 0.f, 0.f, 0.f};

    int4 ar0, ar1, br0, br1;
    ar0 = *(const int4*)(a0p); ar1 = *(const int4*)(a1p);
    br0 = *(const int4*)(b0p); br1 = *(const int4*)(b1p);

    int buf = 0;
    for (int k0 = 0; k0 < E_N; k0 += 32) {
        // commit staged regs to LDS[buf]
        *(int4*)(&As[buf][s_row0 * LDA + s_c * 8]) = ar0;
        *(int4*)(&As[buf][s_row1 * LDA + s_c * 8]) = ar1;
        *(int4*)(&Bs[buf][s_row0 * LDA + s_c * 8]) = br0;
        *(int4*)(&Bs[buf][s_row1 * LDA + s_c * 8]) = br1;
        // issue next stage's global loads (overlap with barrier + compute)
        if (k0 + 32 < E_N) {
            int koff = k0 + 32;
            ar0 = *(const int4*)(a0p + koff);
            ar1 = *(const int4*)(a1p + koff);
            br0 = *(const int4*)(b0p + koff);
            br1 = *(const int4*)(b1p + koff);
        }
        __syncthreads();
        bf16x8 af[4], bfr[4];
#pragma unroll
        for (int i = 0; i < 4; ++i) {
            af[i]  = *(const bf16x8*)(&As[buf][(wm + i * 16 + l15) * LDA + quad * 8]);
            bfr[i] = *(const bf16x8*)(&Bs[buf][(wn + i * 16 + l15) * LDA + quad * 8]);
        }
#pragma unroll
        for (int mi = 0; mi < 4; ++mi)
#pragma unroll
            for (int ni = 0; ni < 4; ++ni)
                acc[mi][ni] = __builtin_amdgcn_mfma_f32_16x16x32_bf16(
                    af[mi], bfr[ni], acc[mi][ni], 0, 0, 0);
        buf ^= 1;
        // no trailing barrier needed: next store targets the buffer last read
        // one full iteration ago, ordered by the next iteration's barrier... but
        // next store happens BEFORE that barrier — ordering comes from THIS
        // barrier having ordered everyone past the read of that buffer.
    }

    // epilogue: gelu(acc + b1) * W2, partial dot over this block's 128 cols
    float pr[4][4];
#pragma unroll
    for (int mi = 0; mi < 4; ++mi)
#pragma unroll
        for (int r = 0; r < 4; ++r) pr[mi][r] = 0.f;
#pragma unroll
    for (int ni = 0; ni < 4; ++ni) {
        int n = n0 + wn + ni * 16 + l15;
        float bb = b1[t * E_N + n];
        float w2 = W2[t * E_N + n];
#pragma unroll
        for (int mi = 0; mi < 4; ++mi)
#pragma unroll
            for (int r = 0; r < 4; ++r) {
                float u = acc[mi][ni][r] + bb;
                float gg = 0.5f * u * (1.f + erff(u * 0.70710678118654752f));
                pr[mi][r] = fmaf(gg, w2, pr[mi][r]);
            }
    }
#pragma unroll
    for (int off = 1; off <= 8; off <<= 1)
#pragma unroll
        for (int mi = 0; mi < 4; ++mi)
#pragma unroll
            for (int r = 0; r < 4; ++r) pr[mi][r] += __shfl_xor(pr[mi][r], off, 64);

    if (l15 == 0) {
#pragma unroll
        for (int mi = 0; mi < 4; ++mi)
#pragma unroll
            for (int r = 0; r < 4; ++r) {
                int row = m0 + wm + mi * 16 + quad * 4 + r;
                if (row < n_t) atomicAdd(&yacc[base + row], pr[mi][r]);
            }
    }
}

__global__ void k_final(const float* __restrict__ yacc, const int* __restrict__ rank,
                        const int* __restrict__ tv, const float* __restrict__ b2,
                        float* __restrict__ out, int use_rank) {
    int b = blockIdx.x * blockDim.x + threadIdx.x;
    if (b < B_N) {
        int idx = use_rank ? rank[b] : b;
        float x = yacc[idx] + b2[tv[b]];
        out[b] = fmaxf(x, 0.f) + log1pf(expf(-fabsf(x)));  // stable softplus
    }
}

// ================= fallback (fp32 path, proven) =================
__global__ __launch_bounds__(256) void fb_gemm(
    const float* __restrict__ g_exp, const float* __restrict__ W1,
    const float* __restrict__ b1, const float* __restrict__ W2,
    const int* __restrict__ offs, const int* __restrict__ order,
    float* __restrict__ yacc) {
    int t = blockIdx.z;
    int base = offs[t];
    int n_t = offs[t + 1] - base;
    int m0 = blockIdx.y * 64;
    if (m0 >= n_t) return;
    int n0 = blockIdx.x * 128;

    __shared__ float As[32][68];
    __shared__ float Bs[32][128];
    __shared__ int sidx[64];

    int tid = threadIdx.x;
    if (tid < 64) {
        int m = m0 + tid;
        sidx[tid] = (m < n_t) ? order[base + m] : -1;
    }
    __syncthreads();

    int ty = tid >> 4, tx = tid & 15;
    float acc[4][8];
#pragma unroll
    for (int r = 0; r < 4; ++r)
#pragma unroll
        for (int c = 0; c < 8; ++c) acc[r][c] = 0.f;

    for (int k0 = 0; k0 < E_N; k0 += 32) {
#pragma unroll
        for (int p = 0; p < 2; ++p) {
            int idx = tid + 256 * p;
            int row = idx >> 3, kc = idx & 7;
            int s = sidx[row];
            float4 v = make_float4(0.f, 0.f, 0.f, 0.f);
            if (s >= 0) v = *(const float4*)(g_exp + (size_t)s * E_N + k0 + kc * 4);
            As[kc * 4 + 0][row] = v.x;
            As[kc * 4 + 1][row] = v.y;
            As[kc * 4 + 2][row] = v.z;
            As[kc * 4 + 3][row] = v.w;
        }
#pragma unroll
        for (int p = 0; p < 4; ++p) {
            int idx = tid + 256 * p;
            int kr = idx >> 5, c4 = idx & 31;
            *(float4*)(&Bs[kr][c4 * 4]) =
                *(const float4*)(W1 + ((size_t)t * E_N + (k0 + kr)) * E_N + n0 + c4 * 4);
        }
        __syncthreads();
#pragma unroll
        for (int e = 0; e < 32; ++e) {
            float4 a = *(const float4*)(&As[e][ty * 4]);
            float4 bA = *(const float4*)(&Bs[e][tx * 4]);
            float4 bB = *(const float4*)(&Bs[e][tx * 4 + 64]);
            float av[4] = {a.x, a.y, a.z, a.w};
            float bv[8] = {bA.x, bA.y, bA.z, bA.w, bB.x, bB.y, bB.z, bB.w};
#pragma unroll
            for (int r = 0; r < 4; ++r)
#pragma unroll
                for (int c = 0; c < 8; ++c) acc[r][c] = fmaf(av[r], bv[c], acc[r][c]);
        }
        __syncthreads();
    }

    float pr[4] = {0.f, 0.f, 0.f, 0.f};
#pragma unroll
    for (int c = 0; c < 8; ++c) {
        int n = n0 + tx * 4 + ((c >= 4) ? 64 : 0) + (c & 3);
        float bb = b1[t * E_N + n];
        float w2 = W2[t * E_N + n];
#pragma unroll
        for (int r = 0; r < 4; ++r) {
            float u = acc[r][c] + bb;
            float g = 0.5f * u * (1.f + erff(u * 0.70710678118654752f));
            pr[r] = fmaf(g, w2, pr[r]);
        }
    }
#pragma unroll
    for (int off = 8; off >= 1; off >>= 1)
#pragma unroll
        for (int r = 0; r < 4; ++r) pr[r] += __shfl_xor(pr[r], off, 64);

    if (tx == 0) {
#pragma unroll
        for (int r = 0; r < 4; ++r) {
            int m = m0 + ty * 4 + r;
            if (m < n_t) atomicAdd(&yacc[sidx[ty * 4 + r]], pr[r]);
        }
    }
}

extern "C" void kernel_launch(void* const* d_in, const int* in_sizes, int n_in,
                              void* d_out, int out_size, void* d_ws, size_t ws_size,
                              hipStream_t stream) {
    const float* g_exp = (const float*)d_in[0];
    const int*   tv    = (const int*)d_in[1];
    const float* W1    = (const float*)d_in[2];
    const float* b1    = (const float*)d_in[3];
    const float* W2    = (const float*)d_in[4];
    const float* b2    = (const float*)d_in[5];
    float* out = (float*)d_out;

    char* ws = (char*)d_ws;
    int* offs   = (int*)(ws + WS_OFFS);
    int* rank   = (int*)(ws + WS_RANK);
    int* order  = (int*)(ws + WS_ORDER);
    float* yacc = (float*)(ws + WS_YACC);

    if (ws_size >= (size_t)WS_REQ) {
        unsigned short* Asort = (unsigned short*)(ws + WS_ASORT);
        unsigned short* W1T   = (unsigned short*)(ws + WS_W1T);
        k_prep<<<1, 1024, 0, stream>>>(tv, offs, rank, order, yacc);
        k_convert<<<2304, 256, 0, stream>>>(W1, W1T, g_exp, rank, Asort);
        k_gemm_mfma<<<512, 256, 0, stream>>>(Asort, W1T, b1, W2, offs, yacc);
        k_final<<<32, 256, 0, stream>>>(yacc, rank, tv, b2, out, 1);
    } else {
        k_prep<<<1, 1024, 0, stream>>>(tv, offs, rank, order, yacc);
        fb_gemm<<<dim3(4, 8, 32), 256, 0, stream>>>(g_exp, W1, b1, W2, offs, order, yacc);
        k_final<<<32, 256, 0, stream>>>(yacc, rank, tv, b2, out, 0);
    }
}